// Round 1
// 299.324 us; speedup vs baseline: 1.1245x; 1.1245x over previous
//
#include <hip/hip_runtime.h>
#include <math.h>

#define IMG_H 512
#define IMG_W 512
#define NCELL 64     // cells per dim (512/8)
#define NORI 9
#define QMAX 128     // slow-path queue capacity (expected usage ~1/block)

// ---------------------------------------------------------------------------
// Bit-exact transcription of glibc/FDLIBM float atan / atan2 (flt-32 Sun code)
// — what numpy's np.arctan2 float32 loop resolves to on glibc <= 2.40.
// Used ONLY for queued near-bin-boundary pixels (~2e-4 of pixels). The
// structural gr==+0 rows are now handled analytically (bin 0, proven exact).
// ---------------------------------------------------------------------------
__device__ __noinline__ float fdlibm_atanf(float x) {
#pragma clang fp contract(off)
    const float atanhi[4] = {4.6364760399e-01f, 7.8539812565e-01f,
                             9.8279368877e-01f, 1.5707962513e+00f};
    const float atanlo[4] = {5.0121582440e-09f, 3.7748947079e-08f,
                             3.4473217170e-08f, 7.5497894159e-08f};
    const float aT[11] = {
        3.3333334327e-01f, -2.0000000298e-01f, 1.4285714924e-01f,
       -1.1111110449e-01f,  9.0908870101e-02f, -7.6918758452e-02f,
        6.6610731184e-02f, -5.8335702866e-02f,  4.9768779427e-02f,
       -3.6531571299e-02f,  1.6285819933e-02f};
    const float one = 1.0f;

    int hx = __float_as_int(x);
    int ix = hx & 0x7fffffff;
    int id;
    if (ix >= 0x4c800000) {                 // |x| >= 2^26
        if (hx > 0) return atanhi[3] + atanlo[3];
        else        return -atanhi[3] - atanlo[3];
    }
    if (ix < 0x3ee00000) {                  // |x| < 0.4375
        if (ix < 0x39800000) {              // |x| < 2^-12
            return x;
        }
        id = -1;
    } else {
        x = fabsf(x);
        if (ix < 0x3f980000) {              // |x| < 1.1875
            if (ix < 0x3f300000) { id = 0; x = (2.0f * x - one) / (2.0f + x); }
            else                 { id = 1; x = (x - one) / (x + one); }
        } else {
            if (ix < 0x401c0000) { id = 2; x = (x - 1.5f) / (one + 1.5f * x); }
            else                 { id = 3; x = -1.0f / x; }
        }
    }
    float z = x * x;
    float w = z * z;
    float s1 = z * (aT[0] + w * (aT[2] + w * (aT[4] + w * (aT[6] + w * (aT[8] + w * aT[10])))));
    float s2 = w * (aT[1] + w * (aT[3] + w * (aT[5] + w * (aT[7] + w * aT[9]))));
    if (id < 0) return x - x * (s1 + s2);
    z = atanhi[id] - ((x * (s1 + s2) - atanlo[id]) - x);
    return (hx < 0) ? -z : z;
}

__device__ __noinline__ int fdlibm_bin(float y, float x) {
#pragma clang fp contract(off)
    // exact reference chain: fdlibm atan2f -> f32 rad2deg -> numpy mod -> bin
    const float tiny   = 1.0e-30f;
    const float pi_o_2 = 1.5707963705e+00f;   // 0x3FC90FDB
    const float pi     = 3.1415927410e+00f;   // 0x40490FDB
    const float pi_lo  = -8.7422776573e-08f;  // 0xB3BBBD2E

    int hx = __float_as_int(x), ix = hx & 0x7fffffff;
    int hy = __float_as_int(y), iy = hy & 0x7fffffff;
    float th;
    if (hx == 0x3f800000) { th = fdlibm_atanf(y); }        // x == 1.0
    else {
        int m = ((hy >> 31) & 1) | ((hx >> 30) & 2);       // 2*sign(x)+sign(y)
        if (iy == 0) {                                      // y == +-0
            switch (m) {
                case 0:
                case 1: th = y; break;
                case 2: th =  pi + tiny; break;
                default: th = -pi - tiny; break;
            }
        } else if (ix == 0) {
            th = (hy < 0) ? -pi_o_2 - tiny : pi_o_2 + tiny; // x == +-0
        } else {
            int k = (iy - ix) >> 23;
            float z;
            int mm = m;
            if (k > 26) {                                   // |y/x| > 2^26
                z = pi_o_2 + 0.5f * pi_lo;
                mm &= 1;
            } else if (k < -26 && hx < 0) {
                z = 0.0f;
            } else {
                z = fdlibm_atanf(fabsf(y / x));
            }
            switch (mm) {
                case 0:  th = z; break;
                case 1:  th = -z; break;
                case 2:  th = pi - (z - pi_lo); break;
                default: th = (z - pi_lo) - pi; break;
            }
        }
    }
    const float RAD2DEG = (float)(180.0 / 3.14159265358979311600e+00);
    float m = fmodf(th * RAD2DEG, 180.0f);                  // numpy remainder semantics
    if (m < 0.0f) m += 180.0f;                              // (can round up to exactly 180)
    int o = (int)(m * 0.05f);
    if (o < 9) {                                            // exact boundary fix-up
        if (m < 20.0f * (float)o) --o;
        else if (m >= 20.0f * (float)(o + 1)) ++o;
    }
    return o;                                               // may be 9 (== exactly 180): no bin
}

// ---------------------------------------------------------------------------
// Fast-path bin computation, call-free. Shared by the hot loop and the
// (practically unreachable) overflow rescan so classification is identical.
// ay==0 (gr==+0.0) is EXACT: reference chain gives bin 0 for any gc
// (atan2(+0,gc>=0)=+0 -> 0 deg; atan2(+0,gc<0)=pi_f32 -> 180.000007 deg
//  rounds to exactly 180.0f -> mod 180 == 0) => o=0, never suspect.
// ---------------------------------------------------------------------------
__device__ __forceinline__ void fast_bin(float gr, float gc,
                                         float& mag, int& o, bool& suspect) {
#pragma clang fp contract(off)
    const float PIF   = 3.14159265358979323846f;
    const float PIO2F = 1.57079632679489662f;
    const float PIO4F = 0.78539816339744831f;

    mag = __builtin_amdgcn_sqrtf(__builtin_fmaf(gr, gr, gc * gc));

    const float ax = fabsf(gc), ay = fabsf(gr);
    const float mx = fmaxf(ax, ay), mn = fminf(ax, ay);
    const bool red = mn > 0.4142135624f * mx;
    const float num = red ? (mn - mx) : mn;
    const float den = red ? (mn + mx) : mx;
    const float xx  = num * __builtin_amdgcn_rcpf(den);  // 1-ulp rcp: err << guard
    const float z   = xx * xx;
    // Cephes atanf minimax, |x|<=0.4142: rel err ~2.4e-8
    float y = __builtin_fmaf(
                __builtin_fmaf(
                  __builtin_fmaf(8.05374449538e-2f, z, -1.38776856032e-1f),
                  z, 1.99777106478e-1f),
                z, -3.33329491539e-1f);
    float r0 = __builtin_fmaf(y * z, xx, xx);           // atan(xx)
    if (red)        r0 = PIO4F + r0;
    if (ay > ax)    r0 = PIO2F - r0;
    if (gc < 0.0f)  r0 = PIF - r0;
    if (gr < 0.0f)  r0 = PIF - r0;
    const float q    = (r0 * 57.295779513082323f) * 0.05f;
    o = (int)q;                                         // (int)NaN==0 on gfx950: safe
    const float frac = q - (float)o;
    suspect = (frac < 1e-4f) || (frac > 0.9999f) || (o > 8);
    if (ay == 0.0f) { o = 0; suspect = false; }         // exact (see above)
}

// ---------------------------------------------------------------------------
// Kernel 1: per-cell orientation histograms.
// v2: NO calls and NO atomics in the hot loop. Register 9-bin histogram per
// thread, 8-lane shfl_xor butterfly per cell, direct coalesced global store.
// Near-boundary pixels (P~2e-4) go to a tiny LDS queue resolved post-loop
// via fdlibm + rare global atomics. Staging issues all 15 float4 loads
// before any LDS write (one latency exposure).
// ---------------------------------------------------------------------------
__global__ __launch_bounds__(256) void hog_hist_kernel(const float* __restrict__ x,
                                                       float* __restrict__ hist) {
#pragma clang fp contract(off)
    const int bid = blockIdx.x;
    const int b   = bid >> 6;     // batch
    const int cr  = bid & 63;     // cell row
    const int t   = threadIdx.x;
    const int h0  = cr * 8;

    __shared__ __align__(16) float g[10][IMG_W];       // 20 KB gray strip + halo rows
    __shared__ float qgr[QMAX], qgc[QMAX], qmag[QMAX]; // slow-path queue (1.5 KB)
    __shared__ int   qcell[QMAX];
    __shared__ int   nslow;

    if (t == 0) nslow = 0;

    // ---- stage gray rows; halo rows MIRRORED so edge gr == +0.0 exactly ----
    const float GW0 = 0.2125f, GW1 = 0.7154f, GW2 = 0.0721f;
    float4 A[5], C[5], D[5];
#pragma unroll
    for (int k = 0; k < 5; ++k) {
        const int gi = t + 256 * k;           // 0..1279
        const int rr = gi >> 7;               // 0..9
        int h = h0 - 1 + rr;
        if (h < 0)   h = 1;                   // g[0]:=gray(row1)=g[2] -> gr=0 at h=0
        if (h > 511) h = 510;                 // g[9]:=gray(row510)=g[7] -> gr=0 at h=511
        const int grp = gi & 127;             // 4-pixel group within row
        const float4* p4 = (const float4*)x + (size_t)(b * IMG_H + h) * (IMG_W * 3 / 4)
                           + (size_t)grp * 3;
        A[k] = p4[0]; C[k] = p4[1]; D[k] = p4[2];   // all 15 loads in flight
    }
#pragma unroll
    for (int k = 0; k < 5; ++k) {
        const int gi = t + 256 * k;
        const int rr = gi >> 7;
        const int wg = (gi & 127) * 4;
        g[rr][wg + 0] = __builtin_fmaf(A[k].z, GW2, __builtin_fmaf(A[k].y, GW1, A[k].x * GW0));
        g[rr][wg + 1] = __builtin_fmaf(C[k].y, GW2, __builtin_fmaf(C[k].x, GW1, A[k].w * GW0));
        g[rr][wg + 2] = __builtin_fmaf(D[k].x, GW2, __builtin_fmaf(C[k].w, GW1, C[k].z * GW0));
        g[rr][wg + 3] = __builtin_fmaf(D[k].w, GW2, __builtin_fmaf(D[k].z, GW1, D[k].y * GW0));
    }
    __syncthreads();

    float* hout = hist + (size_t)(b * NCELL + cr) * (NCELL * NORI);

    // ---- per-pixel gradient, magnitude, orientation bin (call/atomic-free) ----
    for (int pass = 0; pass < 2; ++pass) {
        const int w  = t + pass * 256;          // pixel column 0..511 (stride-1 LDS)
        const int wl = (w == 0)   ? 0   : w - 1;
        const int wr = (w == 511) ? 511 : w + 1;
        const bool wok = (w >= 1) && (w <= 510);
        const int c  = w >> 3;                  // cell column

        // batch-preload: all independent ds_reads issued up front
        float cc[10], ee[8], ww[8];
#pragma unroll
        for (int i = 0; i < 10; ++i) cc[i] = g[i][w];
#pragma unroll
        for (int i = 0; i < 8; ++i) { ee[i] = g[i + 1][wr]; ww[i] = g[i + 1][wl]; }

        float bh[9];
#pragma unroll
        for (int k = 0; k < 9; ++k) bh[k] = 0.0f;

#pragma unroll
        for (int r = 0; r < 8; ++r) {
            const float gr = cc[r + 2] - cc[r];              // +0.0 at image edge rows
            const float gc = wok ? (ee[r] - ww[r]) : 0.0f;
            float mag; int o; bool suspect;
            fast_bin(gr, gc, mag, o, suspect);
            if (suspect) {                                   // rare (~2e-4): defer
                const int qi = atomicAdd(&nslow, 1);
                if (qi < QMAX) { qgr[qi] = gr; qgc[qi] = gc; qmag[qi] = mag; qcell[qi] = c; }
            } else {
#pragma unroll
                for (int k = 0; k < 9; ++k) bh[k] += (o == k) ? mag : 0.0f;
            }
        }

        // reduce the 8 lanes of each cell (lanes are bank-aligned groups of 8)
#pragma unroll
        for (int k = 0; k < 9; ++k) {
            bh[k] += __shfl_xor(bh[k], 1, 64);
            bh[k] += __shfl_xor(bh[k], 2, 64);
            bh[k] += __shfl_xor(bh[k], 4, 64);
        }
        // lane j of the cell stores bin j (contiguous across the wave), lane 0 bin 8
        const int j = t & 7;
        float mv = bh[0];
#pragma unroll
        for (int k = 1; k < 8; ++k) mv = (j == k) ? bh[k] : mv;
        hout[c * NORI + j] = mv * 0.015625f;                 // /64 cell area
        if (j == 0) hout[c * NORI + 8] = bh[8] * 0.015625f;
    }

    __syncthreads();   // all stores to hout issued before fix-up atomics

    const int ns = nslow;
    if (ns <= QMAX) {
        if (t < ns) {                                        // ns <= 128 < 256
            const int o = fdlibm_bin(qgr[t], qgc[t]);
            if (o >= 0 && o <= 8)
                atomicAdd(&hout[qcell[t] * NORI + o], qmag[t] * 0.015625f);
        }
    } else {
        // queue overflow (practically unreachable): deterministic rescan.
        // fast_bin on identical inputs reproduces the exact suspect set.
        for (int pass = 0; pass < 2; ++pass) {
            const int w  = t + pass * 256;
            const int wl = (w == 0)   ? 0   : w - 1;
            const int wr = (w == 511) ? 511 : w + 1;
            const bool wok = (w >= 1) && (w <= 510);
            const int c  = w >> 3;
            for (int r = 0; r < 8; ++r) {
                const float gr = g[r + 2][w] - g[r][w];
                const float gc = wok ? (g[r + 1][wr] - g[r + 1][wl]) : 0.0f;
                float mag; int o; bool suspect;
                fast_bin(gr, gc, mag, o, suspect);
                if (suspect) {
                    const int oo = fdlibm_bin(gr, gc);
                    if (oo >= 0 && oo <= 8)
                        atomicAdd(&hout[c * NORI + oo], mag * 0.015625f);
                }
            }
        }
    }
}

// ---------------------------------------------------------------------------
// Kernel 2: 2x2 block gathering + double L2-hys normalization.
// v2: zero LDS, zero barriers. 4 lanes per output block (one cell each):
// 9 independent dword loads (hist is L2-hot), quad shfl_xor butterflies for
// the two norms, 9 dword stores per lane (block-contiguous => coalesced).
// ---------------------------------------------------------------------------
__global__ __launch_bounds__(256) void hog_norm_kernel(const float* __restrict__ hist,
                                                       float* __restrict__ out) {
#pragma clang fp contract(off)
    const int bid = blockIdx.x;
    const int b   = bid / 63;
    const int r   = bid % 63;
    const int t   = threadIdx.x;
    const int c   = t >> 2;      // block column 0..63 (63 used)
    const int l   = t & 3;       // (i,j) within 2x2
    if (c >= 63) return;

    const int bi = l >> 1, bj = l & 1;
    const float* v = hist + ((size_t)(b * NCELL + r + bi) * NCELL + (c + bj)) * NORI;

    float vv[9];
    float ss = 0.0f;
#pragma unroll
    for (int k = 0; k < 9; ++k) { vv[k] = v[k]; ss += vv[k] * vv[k]; }
    ss += __shfl_xor(ss, 1, 64);
    ss += __shfl_xor(ss, 2, 64);
    const float rn1 = 1.0f / sqrtf(ss + 1e-10f);            // EPS^2 = 1e-10
    float ss2 = 0.0f;
#pragma unroll
    for (int k = 0; k < 9; ++k) { vv[k] = fminf(vv[k] * rn1, 0.2f); ss2 += vv[k] * vv[k]; }
    ss2 += __shfl_xor(ss2, 1, 64);
    ss2 += __shfl_xor(ss2, 2, 64);
    const float rn2 = 1.0f / sqrtf(ss2 + 1e-10f);

    float* od = out + (size_t)bid * (63 * 36) + (c * 36 + l * 9);
#pragma unroll
    for (int k = 0; k < 9; ++k) od[k] = vv[k] * rn2;
}

extern "C" void kernel_launch(void* const* d_in, const int* in_sizes, int n_in,
                              void* d_out, int out_size, void* d_ws, size_t ws_size,
                              hipStream_t stream) {
    const float* x = (const float*)d_in[0];
    float* out     = (float*)d_out;
    float* hist    = (float*)d_ws;   // 64*64*64*9 floats = 9.4 MB scratch

    hog_hist_kernel<<<dim3(64 * 64), dim3(256), 0, stream>>>(x, hist);
    hog_norm_kernel<<<dim3(64 * 63), dim3(256), 0, stream>>>(hist, out);
}